// Round 1
// baseline (470.680 us; speedup 1.0000x reference)
//
#include <hip/hip_runtime.h>
#include <hip/hip_bf16.h>
#include <stdint.h>

// ---------- types ----------
typedef __attribute__((ext_vector_type(8))) short bf8_t;    // 8 bf16 (4 VGPRs)
typedef __attribute__((ext_vector_type(4))) float f32x4_t;

#define MFMA_BF16 __builtin_amdgcn_mfma_f32_16x16x32_bf16

__device__ __forceinline__ unsigned short f2bf(float f) {
  union { float f; unsigned u; } x; x.f = f;
  unsigned r = (x.u + 0x7FFFu + ((x.u >> 16) & 1u)) >> 16;
  return (unsigned short)r;
}
__device__ __forceinline__ float bf2f(unsigned short b) {
  union { unsigned u; float f; } x; x.u = ((unsigned)b) << 16;
  return x.f;
}

// ---------- fp32 -> bf16 convert (n % 8 == 0) ----------
__global__ __launch_bounds__(256) void convert_f32_bf16(
    const float* __restrict__ in, unsigned short* __restrict__ out, int n) {
  int i = (blockIdx.x * 256 + threadIdx.x) * 8;
  if (i >= n) return;
  float4 a = *(const float4*)(in + i);
  float4 b = *(const float4*)(in + i + 4);
  union { bf8_t v; unsigned short s[8]; } o;
  o.s[0] = f2bf(a.x); o.s[1] = f2bf(a.y); o.s[2] = f2bf(a.z); o.s[3] = f2bf(a.w);
  o.s[4] = f2bf(b.x); o.s[5] = f2bf(b.y); o.s[6] = f2bf(b.z); o.s[7] = f2bf(b.w);
  *(bf8_t*)(out + i) = o.v;
}

// ---------- evolution-row scalars: w0, w1 per layer ----------
// A = star K_{1,deg}; G=expm(-iAt) acts as [[cos(rt),-i sin(rt)],[-i sin(rt),cos(rt)]]
// on span{e0,u'}, identity elsewhere; r = sqrt(deg).
// Row 0: G[0,0]=cos(rt), G[0,j]=-i sin(rt)/r.
// GG^H row 0: [a, b/r,...], a=|c|^2+|s|^2, b=-2 Im(c * conj(s)); eigs {a+b, a-b, 1}.
// s2 = max(a+|b|, 1). w0 = c/s + sqrt(1-a/s2); w1 = (-i s/r)/s + csqrt(-b/(r*s2)).
__global__ void compute_wscal(const float* t1r, const float* t1i,
                              const float* t2r, const float* t2i,
                              float* wsc, int deg) {
  if (threadIdx.x != 0 || blockIdx.x != 0) return;
  float r = sqrtf((float)deg);
  for (int l = 0; l < 2; ++l) {
    float tr = l ? t2r[0] : t1r[0];
    float ti = l ? t2i[0] : t1i[0];
    float x = r * tr, y = r * ti;
    float cr = cosf(x) * coshf(y), ci = -sinf(x) * sinhf(y);
    float sr = sinf(x) * coshf(y), si = cosf(x) * sinhf(y);
    float a = cr * cr + ci * ci + sr * sr + si * si;
    float b = -2.0f * (ci * sr - cr * si);
    float s2 = fmaxf(a + fabsf(b), 1.0f);
    float s = sqrtf(s2);
    float l0r = cr / s, l0i = ci / s;          // Lt[0,0]
    float l1r = si / (r * s), l1i = -sr / (r * s); // Lt[0,j]
    float q0 = 1.0f - a / s2;                  // Rt[0,0]^2 (real)
    float r0r = (q0 >= 0.0f) ? sqrtf(q0) : 0.0f;
    float r0i = (q0 >= 0.0f) ? 0.0f : sqrtf(-q0);
    float q1 = -b / (r * s2);                  // Rt[0,j]^2 (real)
    float r1r = (q1 >= 0.0f) ? sqrtf(q1) : 0.0f;
    float r1i = (q1 >= 0.0f) ? 0.0f : sqrtf(-q1);
    wsc[l * 4 + 0] = l0r + r0r;  // w0.re
    wsc[l * 4 + 1] = l0i + r0i;  // w0.im
    wsc[l * 4 + 2] = l1r + r1r;  // w1.re (same for all 16 neighbors)
    wsc[l * 4 + 3] = l1i + r1i;  // w1.im
  }
}

// ---------- neighbor-list build from edge_index (order irrelevant: sum) ----------
__global__ __launch_bounds__(256) void build_nbrs(
    const int* __restrict__ ei, int E, int* __restrict__ cnt,
    int* __restrict__ nbrs, int deg) {
  int e = blockIdx.x * 256 + threadIdx.x;
  if (e >= E) return;
  int s = ei[e], d = ei[E + e];
  int p = atomicAdd(&cnt[s], 1); nbrs[(long)s * deg + p] = d;
  int q = atomicAdd(&cnt[d], 1); nbrs[(long)d * deg + q] = s;
}

// ---------- complex GEMM + bias + crelu ----------
// out[n][c] = crelu( sum_k h[n][k] * W[c][k] + b[c] )
// A-frag: lane holds h[row=lane&15][ks*32 + (lane>>4)*8 + i]   (16B contiguous)
// B-frag: lane holds W[col=lane&15 of cf][same k range]        (16B contiguous)
// D: col = lane&15, row = (lane>>4)*4 + j   [m89-verified]
template <int COMPLEX>
__global__ __launch_bounds__(256) void gemm_crelu(
    const unsigned short* __restrict__ Ar, const unsigned short* __restrict__ Ai,
    const unsigned short* __restrict__ Wr, const unsigned short* __restrict__ Wi,
    const float* __restrict__ br, const float* __restrict__ bi,
    unsigned short* __restrict__ Or, unsigned short* __restrict__ Oi, int n) {
  const int tid = threadIdx.x;
  const int wv = tid >> 6, lane = tid & 63;
  const int rowbase = blockIdx.x * 64 + wv * 16;
  const int fr = lane & 15, kg = lane >> 4;
  const int arow = rowbase + fr;
  const long ar_off = (long)min(arow, n - 1) * 128;

  f32x4_t accr[8], acci[8];
#pragma unroll
  for (int i = 0; i < 8; ++i) {
    accr[i] = (f32x4_t)0.0f;
    acci[i] = (f32x4_t)0.0f;
  }

#pragma unroll
  for (int ks = 0; ks < 4; ++ks) {
    const int koff = ks * 32 + kg * 8;
    bf8_t a_r = *(const bf8_t*)(Ar + ar_off + koff);
    bf8_t a_i = {}, a_in = {};
    if (COMPLEX) {
      a_i = *(const bf8_t*)(Ai + ar_off + koff);
      union { bf8_t v; unsigned u[4]; } t;
      t.v = a_i;
#pragma unroll
      for (int q = 0; q < 4; ++q) t.u[q] ^= 0x80008000u;  // negate bf16 pairs
      a_in = t.v;
    }
#pragma unroll
    for (int cf = 0; cf < 8; ++cf) {
      const int c = cf * 16 + fr;
      bf8_t w_r = *(const bf8_t*)(Wr + c * 128 + koff);
      bf8_t w_i = *(const bf8_t*)(Wi + c * 128 + koff);
      // out_r = hr@Wr^T - hi@Wi^T ; out_i = hr@Wi^T + hi@Wr^T
      accr[cf] = MFMA_BF16(a_r, w_r, accr[cf], 0, 0, 0);
      acci[cf] = MFMA_BF16(a_r, w_i, acci[cf], 0, 0, 0);
      if (COMPLEX) {
        accr[cf] = MFMA_BF16(a_in, w_i, accr[cf], 0, 0, 0);
        acci[cf] = MFMA_BF16(a_i, w_r, acci[cf], 0, 0, 0);
      }
    }
  }

  const int r0 = rowbase + kg * 4;
#pragma unroll
  for (int cf = 0; cf < 8; ++cf) {
    const int c = cf * 16 + fr;
    const float bre = br[c], bie = bi[c];
#pragma unroll
    for (int j = 0; j < 4; ++j) {
      const int rr = r0 + j;
      if (rr < n) {
        float vr = fmaxf(accr[cf][j] + bre, 0.0f);
        float vi = fmaxf(acci[cf][j] + bie, 0.0f);
        Or[(long)rr * 128 + c] = f2bf(vr);
        Oi[(long)rr * 128 + c] = f2bf(vi);
      }
    }
  }
}

// ---------- aggregation: out = w0*h + w1*sum_nbr(h) + eb ----------
// 16 threads per node, 8 channels each. FINAL=1 writes only Re() as fp32.
template <int FINAL>
__global__ __launch_bounds__(256) void agg_kernel(
    const unsigned short* __restrict__ hr, const unsigned short* __restrict__ hi,
    const int* __restrict__ nbrs, const float* __restrict__ wsc,
    const float* __restrict__ ebr, const float* __restrict__ ebi,
    unsigned short* __restrict__ outr, unsigned short* __restrict__ outi,
    float* __restrict__ outf, int n, int deg) {
  const int g = blockIdx.x * 256 + threadIdx.x;
  const int node = g >> 4;
  if (node >= n) return;
  const int ch0 = (g & 15) * 8;
  const float w0r = wsc[0], w0i = wsc[1], w1r = wsc[2], w1i = wsc[3];

  union { bf8_t v; unsigned short s[8]; } ur, ui;
  ur.v = *(const bf8_t*)(hr + (long)node * 128 + ch0);
  ui.v = *(const bf8_t*)(hi + (long)node * 128 + ch0);
  float hrf[8], hif[8], srf[8], sif[8];
#pragma unroll
  for (int e = 0; e < 8; ++e) {
    hrf[e] = bf2f(ur.s[e]); hif[e] = bf2f(ui.s[e]);
    srf[e] = 0.0f; sif[e] = 0.0f;
  }
  const int* nb = nbrs + (long)node * deg;
  for (int k = 0; k < deg; ++k) {
    const long m = (long)nb[k] * 128 + ch0;
    union { bf8_t v; unsigned short s[8]; } vr2, vi2;
    vr2.v = *(const bf8_t*)(hr + m);
    vi2.v = *(const bf8_t*)(hi + m);
#pragma unroll
    for (int e = 0; e < 8; ++e) {
      srf[e] += bf2f(vr2.s[e]);
      sif[e] += bf2f(vi2.s[e]);
    }
  }
#pragma unroll
  for (int e = 0; e < 8; ++e) {
    const int c = ch0 + e;
    float R = w0r * hrf[e] - w0i * hif[e] + w1r * srf[e] - w1i * sif[e] + ebr[c];
    if (FINAL) {
      outf[(long)node * 128 + c] = R;
    } else {
      float I = w0r * hif[e] + w0i * hrf[e] + w1r * sif[e] + w1i * srf[e] + ebi[c];
      outr[(long)node * 128 + c] = f2bf(R);
      outi[(long)node * 128 + c] = f2bf(I);
    }
  }
}

// ---------- launch ----------
extern "C" void kernel_launch(void* const* d_in, const int* in_sizes, int n_in,
                              void* d_out, int out_size, void* d_ws, size_t ws_size,
                              hipStream_t stream) {
  const float* x    = (const float*)d_in[0];
  const int*   ei   = (const int*)d_in[1];
  const float* W1r  = (const float*)d_in[2];
  const float* W1i  = (const float*)d_in[3];
  const float* b1r  = (const float*)d_in[4];
  const float* b1i  = (const float*)d_in[5];
  const float* t1r  = (const float*)d_in[6];
  const float* t1i  = (const float*)d_in[7];
  const float* eb1r = (const float*)d_in[8];
  const float* eb1i = (const float*)d_in[9];
  const float* W2r  = (const float*)d_in[10];
  const float* W2i  = (const float*)d_in[11];
  const float* b2r  = (const float*)d_in[12];
  const float* b2i  = (const float*)d_in[13];
  const float* t2r  = (const float*)d_in[14];
  const float* t2i  = (const float*)d_in[15];
  const float* eb2r = (const float*)d_in[16];
  const float* eb2i = (const float*)d_in[17];

  const int DIM = 128;
  const int N = in_sizes[0] / DIM;   // 100000
  const int E = in_sizes[1] / 2;     // 800000
  const int deg = (2 * E) / N;       // 16

  char* ws = (char*)d_ws;
  size_t off = 0;
  auto alloc = [&](size_t bytes) -> char* {
    char* p = ws + off;
    off += (bytes + 255) & ~(size_t)255;
    return p;
  };
  int* cnt  = (int*)alloc((size_t)N * 4);
  int* nbrs = (int*)alloc((size_t)N * deg * 4);
  float* wsc = (float*)alloc(8 * 4);
  const size_t nW = (size_t)DIM * DIM;
  unsigned short* wb1r = (unsigned short*)alloc(nW * 2);
  unsigned short* wb1i = (unsigned short*)alloc(nW * 2);
  unsigned short* wb2r = (unsigned short*)alloc(nW * 2);
  unsigned short* wb2i = (unsigned short*)alloc(nW * 2);
  const size_t nH = (size_t)N * DIM;
  unsigned short* bufA = (unsigned short*)alloc(nH * 2);  // x_bf16, later h2r
  unsigned short* h1r  = (unsigned short*)alloc(nH * 2);  // later h2i
  unsigned short* h1i  = (unsigned short*)alloc(nH * 2);
  unsigned short* g1r  = (unsigned short*)alloc(nH * 2);
  unsigned short* g1i  = (unsigned short*)alloc(nH * 2);
  (void)ws_size; (void)n_in; (void)out_size;

  hipMemsetAsync(cnt, 0, (size_t)N * 4, stream);
  build_nbrs<<<(E + 255) / 256, 256, 0, stream>>>(ei, E, cnt, nbrs, deg);
  compute_wscal<<<1, 64, 0, stream>>>(t1r, t1i, t2r, t2i, wsc, deg);

  convert_f32_bf16<<<(int)((nW / 8 + 255) / 256), 256, 0, stream>>>(W1r, wb1r, (int)nW);
  convert_f32_bf16<<<(int)((nW / 8 + 255) / 256), 256, 0, stream>>>(W1i, wb1i, (int)nW);
  convert_f32_bf16<<<(int)((nW / 8 + 255) / 256), 256, 0, stream>>>(W2r, wb2r, (int)nW);
  convert_f32_bf16<<<(int)((nW / 8 + 255) / 256), 256, 0, stream>>>(W2i, wb2i, (int)nW);
  convert_f32_bf16<<<(int)((nH / 8 + 255) / 256), 256, 0, stream>>>(x, bufA, (int)nH);

  const int gemm_blocks = (N + 63) / 64;
  const int agg_blocks = (N * 16 + 255) / 256;

  // layer 1 (real input)
  gemm_crelu<0><<<gemm_blocks, 256, 0, stream>>>(bufA, nullptr, wb1r, wb1i,
                                                 b1r, b1i, h1r, h1i, N);
  agg_kernel<0><<<agg_blocks, 256, 0, stream>>>(h1r, h1i, nbrs, wsc, eb1r, eb1i,
                                                g1r, g1i, nullptr, N, deg);
  // layer 2 (complex input); h2r -> bufA, h2i -> h1r (both dead)
  gemm_crelu<1><<<gemm_blocks, 256, 0, stream>>>(g1r, g1i, wb2r, wb2i,
                                                 b2r, b2i, bufA, h1r, N);
  agg_kernel<1><<<agg_blocks, 256, 0, stream>>>(bufA, h1r, nbrs, wsc + 4, eb2r, eb2i,
                                                nullptr, nullptr, (float*)d_out, N, deg);
}

// Round 3
// 346.966 us; speedup vs baseline: 1.3566x; 1.3566x over previous
//
#include <hip/hip_runtime.h>
#include <hip/hip_bf16.h>
#include <stdint.h>

// ---------- types ----------
typedef __attribute__((ext_vector_type(8))) short bf8_t;    // 8 bf16 (4 VGPRs)
typedef __attribute__((ext_vector_type(4))) float f32x4_t;
typedef __attribute__((ext_vector_type(4))) unsigned short us4_t;

#define MFMA_BF16 __builtin_amdgcn_mfma_f32_16x16x32_bf16

__device__ __forceinline__ unsigned short f2bf(float f) {
  union { float f; unsigned u; } x; x.f = f;
  unsigned r = (x.u + 0x7FFFu + ((x.u >> 16) & 1u)) >> 16;
  return (unsigned short)r;
}
__device__ __forceinline__ float bf2f(unsigned short b) {
  union { unsigned u; float f; } x; x.u = ((unsigned)b) << 16;
  return x.f;
}

// ---------- evolution-row scalars: w0, w1 per layer ----------
// A = star K_{1,deg}; G=expm(-iAt) acts as [[cos(rt),-i sin(rt)],[-i sin(rt),cos(rt)]]
// on span{e0,u'}, identity elsewhere; r = sqrt(deg).
__global__ void compute_wscal(const float* t1r, const float* t1i,
                              const float* t2r, const float* t2i,
                              float* wsc, int deg) {
  if (threadIdx.x != 0 || blockIdx.x != 0) return;
  float r = sqrtf((float)deg);
  for (int l = 0; l < 2; ++l) {
    float tr = l ? t2r[0] : t1r[0];
    float ti = l ? t2i[0] : t1i[0];
    float x = r * tr, y = r * ti;
    float cr = cosf(x) * coshf(y), ci = -sinf(x) * sinhf(y);
    float sr = sinf(x) * coshf(y), si = cosf(x) * sinhf(y);
    float a = cr * cr + ci * ci + sr * sr + si * si;
    float b = -2.0f * (ci * sr - cr * si);
    float s2 = fmaxf(a + fabsf(b), 1.0f);
    float s = sqrtf(s2);
    float l0r = cr / s, l0i = ci / s;              // Lt[0,0]
    float l1r = si / (r * s), l1i = -sr / (r * s); // Lt[0,j]
    float q0 = 1.0f - a / s2;                      // Rt[0,0]^2 (real)
    float r0r = (q0 >= 0.0f) ? sqrtf(q0) : 0.0f;
    float r0i = (q0 >= 0.0f) ? 0.0f : sqrtf(-q0);
    float q1 = -b / (r * s2);                      // Rt[0,j]^2 (real)
    float r1r = (q1 >= 0.0f) ? sqrtf(q1) : 0.0f;
    float r1i = (q1 >= 0.0f) ? 0.0f : sqrtf(-q1);
    wsc[l * 4 + 0] = l0r + r0r;  // w0.re
    wsc[l * 4 + 1] = l0i + r0i;  // w0.im
    wsc[l * 4 + 2] = l1r + r1r;  // w1.re (same for all neighbors)
    wsc[l * 4 + 3] = l1i + r1i;  // w1.im
  }
}

// ---------- neighbor-list build (order irrelevant: sum) ----------
__global__ __launch_bounds__(256) void build_nbrs(
    const int* __restrict__ ei, int E, int* __restrict__ cnt,
    int* __restrict__ nbrs, int deg) {
  int e = blockIdx.x * 256 + threadIdx.x;
  if (e >= E) return;
  int s = ei[e], d = ei[E + e];
  int p = atomicAdd(&cnt[s], 1); nbrs[(long)s * deg + p] = d;
  int q = atomicAdd(&cnt[d], 1); nbrs[(long)d * deg + q] = s;
}

// ---------- complex GEMM + bias + crelu, W staged in LDS ----------
// MFMA operands SWAPPED vs naive: A=W (rows=channels), B=h^T (cols=nodes).
// D: col(lane&15)=node, row((lane>>4)*4+j)=channel -> lane holds 4 consecutive
// channels of one node -> packed 8B stores.
// W in LDS: bf16 [plane][c][k], XOR-swizzle byte ^= ((c&7)<<4) to break the
// stride-256B 16-way bank conflict on ds_read_b128 (G4/T2).
template <int COMPLEX>
__global__ __launch_bounds__(512) void gemm_fused(
    const float* __restrict__ Xf,
    const unsigned short* __restrict__ Ar, const unsigned short* __restrict__ Ai,
    const float* __restrict__ Wr, const float* __restrict__ Wi,
    const float* __restrict__ br, const float* __restrict__ bi,
    unsigned short* __restrict__ Or, unsigned short* __restrict__ Oi, int n) {
  __shared__ unsigned char ldsW[65536];
  const int tid = threadIdx.x;

  // ---- stage both W planes: f32 global -> bf16 swizzled LDS (coalesced) ----
#pragma unroll
  for (int p = 0; p < 2; ++p) {
    const float* src = p ? Wi : Wr;
#pragma unroll
    for (int i = 0; i < 4; ++i) {
      const int e8 = (i * 512 + tid) * 8;           // 8 consecutive f32
      float4 a = *(const float4*)(src + e8);
      float4 b = *(const float4*)(src + e8 + 4);
      union { bf8_t v; unsigned short s[8]; } o;
      o.s[0] = f2bf(a.x); o.s[1] = f2bf(a.y); o.s[2] = f2bf(a.z); o.s[3] = f2bf(a.w);
      o.s[4] = f2bf(b.x); o.s[5] = f2bf(b.y); o.s[6] = f2bf(b.z); o.s[7] = f2bf(b.w);
      const int c = e8 >> 7, k = e8 & 127;
      const int byte = p * 32768 + c * 256 + ((k * 2) ^ ((c & 7) << 4));
      *(bf8_t*)(ldsW + byte) = o.v;
    }
  }
  __syncthreads();

  const int wv = tid >> 6, lane = tid & 63;
  const int fr = lane & 15, kg = lane >> 4;
  const int rowbase = blockIdx.x * 128 + wv * 16;
  const int node = min(rowbase + fr, n - 1);
  const long a_off = (long)node * 128;

  f32x4_t accr[8], acci[8];
#pragma unroll
  for (int i = 0; i < 8; ++i) { accr[i] = (f32x4_t)0.0f; acci[i] = (f32x4_t)0.0f; }

#pragma unroll
  for (int ks = 0; ks < 4; ++ks) {
    const int koff = ks * 32 + kg * 8;
    bf8_t a_r, a_i = {}, a_in = {};
    if (COMPLEX) {
      a_r = *(const bf8_t*)(Ar + a_off + koff);
      a_i = *(const bf8_t*)(Ai + a_off + koff);
      union { bf8_t v; unsigned u[4]; } t;
      t.v = a_i;
#pragma unroll
      for (int q = 0; q < 4; ++q) t.u[q] ^= 0x80008000u;  // negate bf16 pairs
      a_in = t.v;
    } else {
      float4 u = *(const float4*)(Xf + a_off + koff);
      float4 v = *(const float4*)(Xf + a_off + koff + 4);
      union { bf8_t vv; unsigned short s[8]; } t;
      t.s[0] = f2bf(u.x); t.s[1] = f2bf(u.y); t.s[2] = f2bf(u.z); t.s[3] = f2bf(u.w);
      t.s[4] = f2bf(v.x); t.s[5] = f2bf(v.y); t.s[6] = f2bf(v.z); t.s[7] = f2bf(v.w);
      a_r = t.vv;
    }
#pragma unroll
    for (int cf = 0; cf < 8; ++cf) {
      const int c = cf * 16 + fr;
      const int wbyte = c * 256 + ((koff * 2) ^ ((c & 7) << 4));
      bf8_t w_r = *(const bf8_t*)(ldsW + wbyte);
      bf8_t w_i = *(const bf8_t*)(ldsW + 32768 + wbyte);
      // out_r = hr@Wr^T - hi@Wi^T ; out_i = hr@Wi^T + hi@Wr^T
      accr[cf] = MFMA_BF16(w_r, a_r, accr[cf], 0, 0, 0);
      acci[cf] = MFMA_BF16(w_i, a_r, acci[cf], 0, 0, 0);
      if (COMPLEX) {
        accr[cf] = MFMA_BF16(w_i, a_in, accr[cf], 0, 0, 0);
        acci[cf] = MFMA_BF16(w_r, a_i, acci[cf], 0, 0, 0);
      }
    }
  }

  // ---- epilogue: bias + crelu, 8B packed stores ----
  const int onode = rowbase + fr;
  if (onode < n) {
    const long obase = (long)onode * 128;
#pragma unroll
    for (int cf = 0; cf < 8; ++cf) {
      const int cb = cf * 16 + kg * 4;     // 4 consecutive channels in this lane
      union { float4 f4; float f[4]; } b4r, b4i;
      b4r.f4 = *(const float4*)(br + cb);
      b4i.f4 = *(const float4*)(bi + cb);
      us4_t pr, pi;
#pragma unroll
      for (int j = 0; j < 4; ++j) {
        pr[j] = f2bf(fmaxf(accr[cf][j] + b4r.f[j], 0.0f));
        pi[j] = f2bf(fmaxf(acci[cf][j] + b4i.f[j], 0.0f));
      }
      *(us4_t*)(Or + obase + cb) = pr;
      *(us4_t*)(Oi + obase + cb) = pi;
    }
  }
}

// ---------- aggregation: out = w0*h + w1*sum_nbr(h) + eb ----------
// 16 threads/node, 8 channels each. DEG>0 -> compile-time unrolled gathers.
template <int DEG, int FINAL>
__global__ __launch_bounds__(256) void agg_kernel(
    const unsigned short* __restrict__ hr, const unsigned short* __restrict__ hi,
    const int* __restrict__ nbrs, const float* __restrict__ wsc,
    const float* __restrict__ ebr, const float* __restrict__ ebi,
    unsigned short* __restrict__ outr, unsigned short* __restrict__ outi,
    float* __restrict__ outf, int n, int deg_rt) {
  const int g = blockIdx.x * 256 + threadIdx.x;
  const int node = g >> 4;
  if (node >= n) return;
  const int ch0 = (g & 15) * 8;
  const int deg = DEG ? DEG : deg_rt;
  const float w0r = wsc[0], w0i = wsc[1], w1r = wsc[2], w1i = wsc[3];

  union { bf8_t v; unsigned short s[8]; } ur, ui;
  ur.v = *(const bf8_t*)(hr + (long)node * 128 + ch0);
  ui.v = *(const bf8_t*)(hi + (long)node * 128 + ch0);
  float hrf[8], hif[8], srf[8], sif[8];
#pragma unroll
  for (int e = 0; e < 8; ++e) {
    hrf[e] = bf2f(ur.s[e]); hif[e] = bf2f(ui.s[e]);
    srf[e] = 0.0f; sif[e] = 0.0f;
  }
  const int* nb = nbrs + (long)node * deg;
#pragma unroll
  for (int k = 0; k < (DEG ? DEG : 1); ++k) {
    for (int kk = DEG ? k : 0; kk < (DEG ? k + 1 : deg); ++kk) {
      const long m = (long)nb[kk] * 128 + ch0;
      union { bf8_t v; unsigned short s[8]; } vr2, vi2;
      vr2.v = *(const bf8_t*)(hr + m);
      vi2.v = *(const bf8_t*)(hi + m);
#pragma unroll
      for (int e = 0; e < 8; ++e) {
        srf[e] += bf2f(vr2.s[e]);
        sif[e] += bf2f(vi2.s[e]);
      }
    }
  }
  if (FINAL) {
    union { float4 f4; float f[4]; } o0, o1;
#pragma unroll
    for (int e = 0; e < 8; ++e) {
      const int c = ch0 + e;
      float R = w0r * hrf[e] - w0i * hif[e] + w1r * srf[e] - w1i * sif[e] + ebr[c];
      if (e < 4) o0.f[e] = R; else o1.f[e - 4] = R;
    }
    *(float4*)(outf + (long)node * 128 + ch0) = o0.f4;
    *(float4*)(outf + (long)node * 128 + ch0 + 4) = o1.f4;
  } else {
    union { bf8_t v; unsigned short s[8]; } pr, pi;
#pragma unroll
    for (int e = 0; e < 8; ++e) {
      const int c = ch0 + e;
      float R = w0r * hrf[e] - w0i * hif[e] + w1r * srf[e] - w1i * sif[e] + ebr[c];
      float I = w0r * hif[e] + w0i * hrf[e] + w1r * sif[e] + w1i * srf[e] + ebi[c];
      pr.s[e] = f2bf(R); pi.s[e] = f2bf(I);
    }
    *(bf8_t*)(outr + (long)node * 128 + ch0) = pr.v;
    *(bf8_t*)(outi + (long)node * 128 + ch0) = pi.v;
  }
}

// ---------- launch ----------
extern "C" void kernel_launch(void* const* d_in, const int* in_sizes, int n_in,
                              void* d_out, int out_size, void* d_ws, size_t ws_size,
                              hipStream_t stream) {
  const float* x    = (const float*)d_in[0];
  const int*   ei   = (const int*)d_in[1];
  const float* W1r  = (const float*)d_in[2];
  const float* W1i  = (const float*)d_in[3];
  const float* b1r  = (const float*)d_in[4];
  const float* b1i  = (const float*)d_in[5];
  const float* t1r  = (const float*)d_in[6];
  const float* t1i  = (const float*)d_in[7];
  const float* eb1r = (const float*)d_in[8];
  const float* eb1i = (const float*)d_in[9];
  const float* W2r  = (const float*)d_in[10];
  const float* W2i  = (const float*)d_in[11];
  const float* b2r  = (const float*)d_in[12];
  const float* b2i  = (const float*)d_in[13];
  const float* t2r  = (const float*)d_in[14];
  const float* t2i  = (const float*)d_in[15];
  const float* eb2r = (const float*)d_in[16];
  const float* eb2i = (const float*)d_in[17];

  const int DIM = 128;
  const int N = in_sizes[0] / DIM;   // 100000
  const int E = in_sizes[1] / 2;     // 800000
  const int deg = (2 * E) / N;       // 16

  char* ws = (char*)d_ws;
  size_t off = 0;
  auto alloc = [&](size_t bytes) -> char* {
    char* p = ws + off;
    off += (bytes + 255) & ~(size_t)255;
    return p;
  };
  int* cnt  = (int*)alloc((size_t)N * 4);
  int* nbrs = (int*)alloc((size_t)N * deg * 4);
  float* wsc = (float*)alloc(8 * 4);
  const size_t nH = (size_t)N * DIM;
  unsigned short* h1r = (unsigned short*)alloc(nH * 2);  // layer1 gemm out / layer2 gemm out (re)
  unsigned short* h1i = (unsigned short*)alloc(nH * 2);  // (im)
  unsigned short* g1r = (unsigned short*)alloc(nH * 2);  // layer1 agg out (re)
  unsigned short* g1i = (unsigned short*)alloc(nH * 2);  // (im)
  (void)ws_size; (void)n_in; (void)out_size;

  hipMemsetAsync(cnt, 0, (size_t)N * 4, stream);
  build_nbrs<<<(E + 255) / 256, 256, 0, stream>>>(ei, E, cnt, nbrs, deg);
  compute_wscal<<<1, 64, 0, stream>>>(t1r, t1i, t2r, t2i, wsc, deg);

  const int gemm_blocks = (N + 127) / 128;
  const int agg_blocks = (N * 16 + 255) / 256;

  // layer 1 (real f32 input, converted in-register)
  gemm_fused<0><<<gemm_blocks, 512, 0, stream>>>(x, nullptr, nullptr, W1r, W1i,
                                                 b1r, b1i, h1r, h1i, N);
  if (deg == 16) {
    agg_kernel<16, 0><<<agg_blocks, 256, 0, stream>>>(h1r, h1i, nbrs, wsc, eb1r, eb1i,
                                                      g1r, g1i, nullptr, N, deg);
  } else {
    agg_kernel<0, 0><<<agg_blocks, 256, 0, stream>>>(h1r, h1i, nbrs, wsc, eb1r, eb1i,
                                                     g1r, g1i, nullptr, N, deg);
  }
  // layer 2 (complex input); outputs overwrite h1 planes (dead after agg1)
  gemm_fused<1><<<gemm_blocks, 512, 0, stream>>>(nullptr, g1r, g1i, W2r, W2i,
                                                 b2r, b2i, h1r, h1i, N);
  if (deg == 16) {
    agg_kernel<16, 1><<<agg_blocks, 256, 0, stream>>>(h1r, h1i, nbrs, wsc + 4, eb2r, eb2i,
                                                      nullptr, nullptr, (float*)d_out, N, deg);
  } else {
    agg_kernel<0, 1><<<agg_blocks, 256, 0, stream>>>(h1r, h1i, nbrs, wsc + 4, eb2r, eb2i,
                                                     nullptr, nullptr, (float*)d_out, N, deg);
  }
}